// Round 13
// baseline (258.989 us; speedup 1.0000x reference)
//
#include <hip/hip_runtime.h>
#include <cstdint>

typedef unsigned short u16;   // bf16 bit pattern
typedef unsigned int   u32;
typedef __attribute__((ext_vector_type(8))) __bf16 bf16x8;
typedef __attribute__((ext_vector_type(2))) float  f32x2;
typedef __attribute__((ext_vector_type(4))) float  f32x4;
typedef __attribute__((ext_vector_type(2))) u32    u32x2;
typedef __attribute__((ext_vector_type(4))) u32    u32x4;

#define N_IMG 4
#define C_DIM 256
#define H_DIM 128
#define W_DIM 128
#define HW    (H_DIM * W_DIM)      // 16384
#define M_TOT (N_IMG * HW)         // 65536
#define CG    64
#define PADOFF 112
#define NCAT  368                  // 256 value cols + 112 offset cols
#define EPSV  1e-5f

__device__ __forceinline__ u16 f2b(float f) {
  u32 u = __float_as_uint(f);
  u += 0x7fffu + ((u >> 16) & 1u);   // round-to-nearest-even
  return (u16)(u >> 16);
}

// async global->LDS, 16B per lane; LDS dest = wave-uniform base + lane*16
__device__ __forceinline__ void async_cp16(const void* g, void* l) {
  __builtin_amdgcn_global_load_lds(
      (const __attribute__((address_space(1))) void*)g,
      (__attribute__((address_space(3))) void*)l, 16, 0, 0);
}

// all four weight tensors f32 -> bf16 in ONE launch.
// f32x4 segment sizes: conv 16384 | value 16384 | offset 7168 | out 16384
// total 56320 = 220 blocks * 256 threads exactly.
__global__ __launch_bounds__(256) void cast_all(
    const float* __restrict__ a0, u16* __restrict__ o0,
    const float* __restrict__ a1, u16* __restrict__ o1,
    const float* __restrict__ a2, u16* __restrict__ o2,
    const float* __restrict__ a3, u16* __restrict__ o3) {
  int i = blockIdx.x * 256 + threadIdx.x;
  const float* in; u16* out; int base;
  if (i < 16384)      { in = a0; out = o0; base = 0; }
  else if (i < 32768) { in = a1; out = o1; base = 16384; }
  else if (i < 39936) { in = a2; out = o2; base = 32768; }
  else                { in = a3; out = o3; base = 39936; }
  int j = i - base;
  f32x4 v = reinterpret_cast<const f32x4*>(in)[j];
  u32 lo = (u32)f2b(v[0]) | ((u32)f2b(v[1]) << 16);
  u32 hi = (u32)f2b(v[2]) | ((u32)f2b(v[3]) << 16);
  reinterpret_cast<u32*>(out)[2 * j]     = lo;
  reinterpret_cast<u32*>(out)[2 * j + 1] = hi;
}

// ---------------------------------------------------------------------------
// FUSED projection kernel v3: BM 128 -> 64 for occupancy.
// r12 counters (BM=128): MfmaUtil 12, VALUBusy 26, HBM 20%, occ 18.6% -- no
// pipe >1/4 busy => latency-bound at 2 blocks/CU (LDS 80K capped by T 64K).
// BM=64: T[64][256]=32K, As 8K (stage-1 uses half; stage-2 ping buffer),
// Bs 8K => 48 KiB => 3 blocks/CU (24 waves), grid 1024.
// Geometry: 4 waves x (64x32) output strips (wn=wave*32, acc[4][2]).
// A-staging: 4ch x 2px per thread, b64 LDS writes, slot-XOR c^(row&3) on
// BOTH write and read (reg-staged path). Same K-order per output element
// as r12 -> bit-identical output.
// Stage 2: counted-vmcnt ping-pong (r11-verified), acc[4][2].
// ---------------------------------------------------------------------------
__global__ __launch_bounds__(256, 3) void fused_proj(
    const float* __restrict__ X, const u16* __restrict__ Bc,
    const u16* __restrict__ Wcat,
    u16* __restrict__ Vv, float* __restrict__ Om,
    const float* __restrict__ vbias, const float* __restrict__ obias,
    const float* __restrict__ gamma, const float* __restrict__ beta,
    const float* __restrict__ mean, const float* __restrict__ var) {
  constexpr int BM = 64, BK = 32;
  __shared__ __align__(16) u16 T[BM * C_DIM];   // 32 KiB, swizzled
  __shared__ __align__(16) u16 As[128 * BK];    // 8 KiB
  __shared__ __align__(16) u16 Bs[128 * BK];    // 8 KiB
  const int tid  = threadIdx.x;
  const int lane = tid & 63;
  const int wave = tid >> 6;
  const int quad = lane >> 4;
  const int l16  = lane & 15;
  const int bm = blockIdx.x * BM;
  const int wn = wave * 32;          // 4 waves cover 128 cols
  const int img = bm >> 14;          // BM=64 divides HW
  const int hw0 = bm & (HW - 1);
  const int px  = (tid & 31) * 2;    // pixel pair within 64-px tile
  const int hh4 = tid >> 5;          // channel-slot 0..7 (4 ch each)
  const float* xb = X + (size_t)img * C_DIM * HW + hw0 + px;

  // ================= stage 1: T = silu(bn1(x @ wc^T)), B in two halves
  f32x4 acc0[4][2] = {};
  f32x4 acc1[4][2] = {};
  for (int ko = 0; ko < C_DIM; ko += BK) {
    // ---- A once: 4 channels x 2 pixels, f32 -> bf16 -> LDS (swizzled slots)
    float a0[4], a1[4];
#pragma unroll
    for (int j = 0; j < 4; ++j) {
      f32x2 fv = *reinterpret_cast<const f32x2*>(
          xb + (size_t)(ko + hh4 * 4 + j) * HW);
      a0[j] = fv.x; a1[j] = fv.y;
    }
    u32x2 wv0, wv1;
    wv0[0] = (u32)f2b(a0[0]) | ((u32)f2b(a0[1]) << 16);
    wv0[1] = (u32)f2b(a0[2]) | ((u32)f2b(a0[3]) << 16);
    wv1[0] = (u32)f2b(a1[0]) | ((u32)f2b(a1[1]) << 16);
    wv1[1] = (u32)f2b(a1[2]) | ((u32)f2b(a1[3]) << 16);
    {
      char* Ab = (char*)As;
      int c  = hh4 >> 1;             // 8-ch chunk 0..3
      int hf = (hh4 & 1) * 8;        // byte half within chunk
      *reinterpret_cast<u32x2*>(
          Ab + px * 64 + (c ^ (px & 3)) * 16 + hf) = wv0;
      *reinterpret_cast<u32x2*>(
          Ab + (px + 1) * 64 + (c ^ ((px + 1) & 3)) * 16 + hf) = wv1;
    }
    // ---- B half 0 (conv_w rows 0..127)
#pragma unroll
    for (int it = 0; it < 2; ++it) {
      int chunk = it * 256 + tid;
      int r  = chunk >> 2;
      int kk = (chunk & 3) << 3;
      async_cp16(Bc + (size_t)r * C_DIM + (ko + kk),
                 Bs + (size_t)(it * 256 + wave * 64) * 8);
    }
    __syncthreads();
    const char* Ab = (const char*)As;
    const bf16x8* Bpf = reinterpret_cast<const bf16x8*>(Bs);
    bf16x8 af[4];
#pragma unroll
    for (int mi = 0; mi < 4; ++mi) {
      int row = mi * 16 + l16;
      af[mi] = *reinterpret_cast<const bf16x8*>(
          Ab + row * 64 + ((quad ^ (row & 3)) * 16));
    }
    {
      bf16x8 bfr[2];
#pragma unroll
      for (int ni = 0; ni < 2; ++ni)
        bfr[ni] = Bpf[(wn + ni * 16 + l16) * 4 + quad];
#pragma unroll
      for (int mi = 0; mi < 4; ++mi)
#pragma unroll
        for (int ni = 0; ni < 2; ++ni)
          acc0[mi][ni] = __builtin_amdgcn_mfma_f32_16x16x32_bf16(
              af[mi], bfr[ni], acc0[mi][ni], 0, 0, 0);
    }
    __syncthreads();   // all waves done reading Bs (half 0)
    // ---- B half 1 (conv_w rows 128..255), reuse Bs
#pragma unroll
    for (int it = 0; it < 2; ++it) {
      int chunk = it * 256 + tid;
      int r  = chunk >> 2;
      int kk = (chunk & 3) << 3;
      async_cp16(Bc + (size_t)(128 + r) * C_DIM + (ko + kk),
                 Bs + (size_t)(it * 256 + wave * 64) * 8);
    }
    __syncthreads();
    {
      bf16x8 bfr[2];
#pragma unroll
      for (int ni = 0; ni < 2; ++ni)
        bfr[ni] = Bpf[(wn + ni * 16 + l16) * 4 + quad];
#pragma unroll
      for (int mi = 0; mi < 4; ++mi)
#pragma unroll
        for (int ni = 0; ni < 2; ++ni)
          acc1[mi][ni] = __builtin_amdgcn_mfma_f32_16x16x32_bf16(
              af[mi], bfr[ni], acc1[mi][ni], 0, 0, 0);
    }
    __syncthreads();   // guard As/Bs overwrite next ko
  }
  // ---- epilogue: bn1 + silu -> T (LDS, swizzled), both halves
  auto epi1 = [&](f32x4 (&acc)[4][2], int bn) {
#pragma unroll
    for (int ni = 0; ni < 2; ++ni) {
      int n = bn + wn + ni * 16 + l16;
      float sc = gamma[n] * rsqrtf(var[n] + EPSV);
      float sh = beta[n] - mean[n] * sc;
#pragma unroll
      for (int mi = 0; mi < 4; ++mi) {
        int row = mi * 16 + quad * 4;
#pragma unroll
        for (int i = 0; i < 4; ++i) {
          float y = acc[mi][ni][i] * sc + sh;
          y = y / (1.f + __expf(-y));   // silu
          int rr = row + i;
          T[rr * C_DIM + (((n >> 3) ^ (rr & 15)) << 3) + (n & 7)] = f2b(y);
        }
      }
    }
  };
  epi1(acc0, 0);
  epi1(acc1, 128);
  __syncthreads();   // T complete; As/Bs free for stage 2

  // ================= stage 2: [vv|om] = T @ wcat^T, counted-vmcnt dbuf
  auto stage2 = [&](u16* buf, int n0, int ko) {
#pragma unroll
    for (int it = 0; it < 2; ++it) {
      int chunk = it * 256 + tid;
      int r  = chunk >> 2;
      int kk = (chunk & 3) << 3;
      int br = n0 + r; if (br >= NCAT) br = NCAT - 1;   // clamp pad rows
      async_cp16(Wcat + (size_t)br * C_DIM + (ko + kk),
                 buf + (size_t)(it * 256 + wave * 64) * 8);
    }
  };
  for (int nc = 0; nc < 3; ++nc) {
    const int n0 = nc * 128;
    f32x4 acc[4][2] = {};
    stage2(As, n0, 0);                       // prologue -> buf0
    for (int koi = 0; koi < 8; ++koi) {
      const u16* cur = (koi & 1) ? Bs : As;
      u16*       nxt = (koi & 1) ? As : Bs;
      if (koi < 7) {
        stage2(nxt, n0, (koi + 1) * BK);     // keep 2 loads in flight
        asm volatile("s_waitcnt vmcnt(2)" ::: "memory");   // cur buf landed
      } else {
        asm volatile("s_waitcnt vmcnt(0)" ::: "memory");
      }
      __builtin_amdgcn_sched_barrier(0);
      __builtin_amdgcn_s_barrier();          // all waves: cur ready
      __builtin_amdgcn_sched_barrier(0);
      const bf16x8* Bpf = reinterpret_cast<const bf16x8*>(cur);
      bf16x8 af[4], bfr[2];
#pragma unroll
      for (int mi = 0; mi < 4; ++mi) {
        int row = mi * 16 + l16;
        int ch  = koi * 4 + quad;            // wanted 8-elem chunk
        af[mi] = *reinterpret_cast<const bf16x8*>(
            &T[row * C_DIM + ((ch ^ (row & 15)) << 3)]);
      }
#pragma unroll
      for (int ni = 0; ni < 2; ++ni)
        bfr[ni] = Bpf[(wn + ni * 16 + l16) * 4 + quad];
#pragma unroll
      for (int mi = 0; mi < 4; ++mi)
#pragma unroll
        for (int ni = 0; ni < 2; ++ni)
          acc[mi][ni] = __builtin_amdgcn_mfma_f32_16x16x32_bf16(
              af[mi], bfr[ni], acc[mi][ni], 0, 0, 0);
      __builtin_amdgcn_sched_barrier(0);
      __builtin_amdgcn_s_barrier();          // all waves consumed cur
    }
    // ---- epilogue: value -> bf16 NHWC, offset -> f32 (M,112)
#pragma unroll
    for (int ni = 0; ni < 2; ++ni) {
      int n = n0 + wn + ni * 16 + l16;
      if (n < C_DIM) {
        float sh = vbias[n];
#pragma unroll
        for (int mi = 0; mi < 4; ++mi) {
          int mrow = bm + mi * 16 + quad * 4;
#pragma unroll
          for (int i = 0; i < 4; ++i)
            Vv[(size_t)(mrow + i) * C_DIM + n] = f2b(acc[mi][ni][i] + sh);
        }
      } else {
        int col = n - C_DIM;
        bool ok = col < PADOFF;
        float sh = ok ? obias[col] : 0.f;
#pragma unroll
        for (int mi = 0; mi < 4; ++mi) {
          int mrow = bm + mi * 16 + quad * 4;
#pragma unroll
          for (int i = 0; i < 4; ++i)
            if (ok) Om[(size_t)(mrow + i) * PADOFF + col] = acc[mi][ni][i] + sh;
        }
      }
    }
  }
}

// ---------------------------------------------------------------------------
// Output GEMM v2 (r12, proven -8.8us): counted-vmcnt double-buffer, BK=32
// ping-pong, LDS 32 KiB. Mid-loop s_waitcnt vmcnt(4); raw s_barrier +
// sched_barrier(0) fences. Bit-identical accumulation.
// Epilogue: bias+bn2+silu -> f32 NCHW DIRECT.
// ---------------------------------------------------------------------------
__global__ __launch_bounds__(256) void gemm_out(
    const u16* __restrict__ A, const u16* __restrict__ B,
    float* __restrict__ Cf,
    const float* __restrict__ bias,
    const float* __restrict__ gamma, const float* __restrict__ beta,
    const float* __restrict__ mean, const float* __restrict__ var) {
  constexpr int BM = 128, BK = 32;
  __shared__ __align__(16) u16 As[2][BM * BK];   // 2 x 8 KiB
  __shared__ __align__(16) u16 Bs[2][BM * BK];   // 2 x 8 KiB
  const int tid  = threadIdx.x;
  const int lane = tid & 63;
  const int wave = tid >> 6;
  const int quad = lane >> 4;
  const int l16  = lane & 15;
  const int bm = blockIdx.x * BM;
  const int bn = blockIdx.y * BM;
  const int wm = (wave & 1) * 64;
  const int wn = (wave >> 1) * 64;

  auto stage = [&](int buf, int ko) {
#pragma unroll
    for (int it = 0; it < 2; ++it) {
      int chunk = it * 256 + tid;          // 16B chunk id, 512 per tile
      int r  = chunk >> 2;                 // tile row 0..127
      int kk = (chunk & 3) << 3;           // k offset 0,8,16,24
      async_cp16(A + (size_t)(bm + r) * C_DIM + (ko + kk),
                 &As[buf][(it * 256 + wave * 64) * 8]);
      async_cp16(B + (size_t)(bn + r) * C_DIM + (ko + kk),
                 &Bs[buf][(it * 256 + wave * 64) * 8]);
    }
  };

  f32x4 acc[4][4] = {};

  stage(0, 0);                             // prologue -> buf0
  for (int t = 0; t < 8; ++t) {
    const int cur = t & 1;
    if (t < 7) {
      stage(cur ^ 1, (t + 1) * BK);        // keep 4 loads in flight
      asm volatile("s_waitcnt vmcnt(4)" ::: "memory");   // tile-t loads landed
    } else {
      asm volatile("s_waitcnt vmcnt(0)" ::: "memory");
    }
    __builtin_amdgcn_sched_barrier(0);
    __builtin_amdgcn_s_barrier();          // all waves: cur ready
    __builtin_amdgcn_sched_barrier(0);
    const bf16x8* Ap = reinterpret_cast<const bf16x8*>(As[cur]);
    const bf16x8* Bp = reinterpret_cast<const bf16x8*>(Bs[cur]);
    bf16x8 af[4], bfr[4];
#pragma unroll
    for (int mi = 0; mi < 4; ++mi) af[mi] = Ap[(wm + mi * 16 + l16) * 4 + quad];
#pragma unroll
    for (int ni = 0; ni < 4; ++ni) bfr[ni] = Bp[(wn + ni * 16 + l16) * 4 + quad];
#pragma unroll
    for (int mi = 0; mi < 4; ++mi)
#pragma unroll
      for (int ni = 0; ni < 4; ++ni)
        acc[mi][ni] = __builtin_amdgcn_mfma_f32_16x16x32_bf16(
            af[mi], bfr[ni], acc[mi][ni], 0, 0, 0);
    __builtin_amdgcn_sched_barrier(0);
    __builtin_amdgcn_s_barrier();          // all waves consumed cur
  }

#pragma unroll
  for (int ni = 0; ni < 4; ++ni) {
    int n = bn + wn + ni * 16 + l16;
    float sc = gamma[n] * rsqrtf(var[n] + EPSV);
    float sh = beta[n] - mean[n] * sc + bias[n] * sc;
#pragma unroll
    for (int mi = 0; mi < 4; ++mi) {
      int mrow = bm + wm + mi * 16 + quad * 4;
      int img = mrow >> 14;            // BM=128 divides HW -> uniform img
      int hw  = mrow & (HW - 1);
      f32x4 y;
#pragma unroll
      for (int i = 0; i < 4; ++i) {
        float z = acc[mi][ni][i] * sc + sh;
        y[i] = z / (1.f + __expf(-z));   // silu
      }
      *reinterpret_cast<f32x4*>(
          Cf + (size_t)img * C_DIM * HW + (size_t)n * HW + hw) = y;
    }
  }
}

// ---------------------------------------------------------------------------
// Deformable sampling, v6 (proven r4: 40 VGPR, occ 50%, ~51us):
// dot2-packed inner loop — v_perm pairs horizontal corners' bf16 channels,
// v_dot2_f32_bf16 applies both corner weights in one instr; weights packed
// via v_cvt_pk_bf16_f32; output packed via cvt_pk. XCD swizzle for L2.
// v: (M, C) NHWC bf16 ; om: (M, 112) f32 [per g: 18 offsets(x,y), 9 masks]
// ---------------------------------------------------------------------------
__global__ __launch_bounds__(256) void dcn_sample(
    const u16* __restrict__ v, const float* __restrict__ om,
    u16* __restrict__ outp) {
  __shared__ float sm[16 * PADOFF];   // 1792 f32 = 7 KiB
  const int tid = threadIdx.x;
  // XCD swizzle (gridDim.x = 4096, divisible by 8 -> bijective)
  const int bid = blockIdx.x;
  const int cpx = gridDim.x >> 3;               // blocks per XCD chunk
  const int wg  = (bid & 7) * cpx + (bid >> 3);
  const int m0  = wg * 16;
  {
    const float* src = om + (size_t)m0 * PADOFF;
#pragma unroll
    for (int i = 0; i < 7; ++i) sm[tid + i * 256] = src[tid + i * 256];
  }
  __syncthreads();
  const int c4 = tid & 3;            // 16-channel slice within group
  const int g  = (tid >> 2) & 3;
  const int pl = tid >> 4;           // pixel within block
  const int m  = m0 + pl;
  const int n  = m >> 14;            // HW = 2^14
  const int hw = m & (HW - 1);
  const int h = hw >> 7, w = hw & 127;
  const float* p = sm + pl * PADOFF + g * 27;
  const u16* vb = v + (size_t)n * HW * C_DIM + g * CG + c4 * 16;
  float acc[16] = {};
#pragma unroll
  for (int k = 0; k < 9; ++k) {
    const int di = k / 3 - 1, dj = k % 3 - 1;
    float ox = p[2 * k], oy = p[2 * k + 1], mk = p[18 + k];
    float lh = (float)(h + di) + oy;
    float lw = (float)(w + dj) + ox;
    float fh = floorf(lh), fw = floorf(lw);
    float dh = lh - fh, dw = lw - fw;
    int h0 = (int)fh, w0 = (int)fw;
    float wy0 = (1.f - dh) * mk, wy1 = dh * mk;
    float wx0 = 1.f - dw, wx1 = dw;
    bool okw0 = (u32)w0 < (u32)W_DIM;
    bool okw1 = (u32)(w0 + 1) < (u32)W_DIM;
    int w0c = min(max(w0, 0), W_DIM - 1);
    int w1c = min(max(w0 + 1, 0), W_DIM - 1);
#pragma unroll
    for (int cy = 0; cy < 2; ++cy) {
      int hh = h0 + cy;
      bool okh = (u32)hh < (u32)H_DIM;
      int hc = min(max(hh, 0), H_DIM - 1);
      const u16* rowp = vb + (size_t)(hc << 7) * C_DIM;
      const u16* qA = rowp + (size_t)w0c * C_DIM;
      const u16* qB = rowp + (size_t)w1c * C_DIM;
      u32x4 a0 = *reinterpret_cast<const u32x4*>(qA);
      u32x4 a1 = *reinterpret_cast<const u32x4*>(qA + 8);
      u32x4 b0 = *reinterpret_cast<const u32x4*>(qB);
      u32x4 b1 = *reinterpret_cast<const u32x4*>(qB + 8);
      float wyc = (cy == 0) ? wy0 : wy1;
      float wtA = (okh && okw0) ? wyc * wx0 : 0.f;
      float wtB = (okh && okw1) ? wyc * wx1 : 0.f;
      u32 wp;
      asm("v_cvt_pk_bf16_f32 %0, %1, %2" : "=v"(wp) : "v"(wtA), "v"(wtB));
#pragma unroll
      for (int j = 0; j < 4; ++j) {
        u32 lo0 = __builtin_amdgcn_perm(a0[j], b0[j], 0x01000504u);
        u32 hi0 = __builtin_amdgcn_perm(a0[j], b0[j], 0x03020706u);
        u32 lo1 = __builtin_amdgcn_perm(a1[j], b1[j], 0x01000504u);
        u32 hi1 = __builtin_amdgcn_perm(a1[j], b1[j], 0x03020706u);
        asm("v_dot2_f32_bf16 %0, %1, %2, %3"
            : "=v"(acc[2 * j]) : "v"(lo0), "v"(wp), "v"(acc[2 * j]));
        asm("v_dot2_f32_bf16 %0, %1, %2, %3"
            : "=v"(acc[2 * j + 1]) : "v"(hi0), "v"(wp), "v"(acc[2 * j + 1]));
        asm("v_dot2_f32_bf16 %0, %1, %2, %3"
            : "=v"(acc[8 + 2 * j]) : "v"(lo1), "v"(wp), "v"(acc[8 + 2 * j]));
        asm("v_dot2_f32_bf16 %0, %1, %2, %3"
            : "=v"(acc[8 + 2 * j + 1]) : "v"(hi1), "v"(wp), "v"(acc[8 + 2 * j + 1]));
      }
    }
  }
  u32x4 r0, r1;
#pragma unroll
  for (int j = 0; j < 4; ++j) {
    u32 pa, pb;
    asm("v_cvt_pk_bf16_f32 %0, %1, %2"
        : "=v"(pa) : "v"(acc[2 * j]), "v"(acc[2 * j + 1]));
    asm("v_cvt_pk_bf16_f32 %0, %1, %2"
        : "=v"(pb) : "v"(acc[8 + 2 * j]), "v"(acc[8 + 2 * j + 1]));
    r0[j] = pa; r1[j] = pb;
  }
  u16* o = outp + (size_t)m * C_DIM + g * CG + c4 * 16;
  *reinterpret_cast<u32x4*>(o)     = r0;
  *reinterpret_cast<u32x4*>(o + 8) = r1;
}

// ---------------------------------------------------------------------------
extern "C" void kernel_launch(void* const* d_in, const int* in_sizes, int n_in,
                              void* d_out, int out_size, void* d_ws, size_t ws_size,
                              hipStream_t stream) {
  const float* x        = (const float*)d_in[0];
  const float* conv_w   = (const float*)d_in[1];
  const float* bn1_g    = (const float*)d_in[2];
  const float* bn1_b    = (const float*)d_in[3];
  const float* bn1_m    = (const float*)d_in[4];
  const float* bn1_v    = (const float*)d_in[5];
  const float* value_w  = (const float*)d_in[6];
  const float* value_b  = (const float*)d_in[7];
  const float* offset_w = (const float*)d_in[8];
  const float* offset_b = (const float*)d_in[9];
  const float* out_w    = (const float*)d_in[10];
  const float* out_b    = (const float*)d_in[11];
  const float* bn2_g    = (const float*)d_in[12];
  const float* bn2_b    = (const float*)d_in[13];
  const float* bn2_m    = (const float*)d_in[14];
  const float* bn2_v    = (const float*)d_in[15];

  char* ws = (char*)d_ws;
  u16*   vv   = (u16*)(ws);                    // 32 MiB  (value proj)
  float* om   = (float*)(ws + 33554432);       // 28 MiB  (offset+mask f32)
  u16*   dcn  = (u16*)(ws + 67108864);         // 32 MiB  (dcn output)
  u16*   wc   = (u16*)(ws + 100663296);        // conv_w bf16 (128 KiB)
  u16*   wcat = (u16*)(ws + 100794368);        // [value_w; offset_w] bf16
  u16*   wout = (u16*)(ws + 100982784);        // out_w bf16 (128 KiB)
  float* outp = (float*)d_out;                 // final output is f32

  // W: all weights f32 -> bf16 in one launch (value+offset concatenated)
  cast_all<<<220, 256, 0, stream>>>(conv_w, wc, value_w, wcat,
                                    offset_w, wcat + 65536, out_w, wout);

  // K1+K2 fused: x -> (conv+bn1+silu in LDS) -> [vv | om]   (BM=64, 3/CU)
  fused_proj<<<dim3(M_TOT / 64), 256, 0, stream>>>(
      x, wc, wcat, vv, om, value_b, offset_b,
      bn1_g, bn1_b, bn1_m, bn1_v);
  // K4: deformable bilinear sampling (16 px / block)
  dcn_sample<<<dim3(M_TOT / 16), 256, 0, stream>>>(vv, om, dcn);
  // K5: d_out = silu(bn2(dcn @ out_w^T + out_b))  f32 NCHW DIRECT
  gemm_out<<<dim3(M_TOT / 128, 2), 256, 0, stream>>>(
      dcn, wout, outp, out_b, bn2_g, bn2_b, bn2_m, bn2_v);
}

// Round 14
// 251.227 us; speedup vs baseline: 1.0309x; 1.0309x over previous
//
#include <hip/hip_runtime.h>
#include <cstdint>

typedef unsigned short u16;   // bf16 bit pattern
typedef unsigned int   u32;
typedef __attribute__((ext_vector_type(8))) __bf16 bf16x8;
typedef __attribute__((ext_vector_type(2))) float  f32x2;
typedef __attribute__((ext_vector_type(4))) float  f32x4;
typedef __attribute__((ext_vector_type(4))) u32    u32x4;

#define N_IMG 4
#define C_DIM 256
#define H_DIM 128
#define W_DIM 128
#define HW    (H_DIM * W_DIM)      // 16384
#define M_TOT (N_IMG * HW)         // 65536
#define CG    64
#define PADOFF 112
#define NCAT  368                  // 256 value cols + 112 offset cols
#define EPSV  1e-5f

__device__ __forceinline__ u16 f2b(float f) {
  u32 u = __float_as_uint(f);
  u += 0x7fffu + ((u >> 16) & 1u);   // round-to-nearest-even
  return (u16)(u >> 16);
}

// async global->LDS, 16B per lane; LDS dest = wave-uniform base + lane*16
__device__ __forceinline__ void async_cp16(const void* g, void* l) {
  __builtin_amdgcn_global_load_lds(
      (const __attribute__((address_space(1))) void*)g,
      (__attribute__((address_space(3))) void*)l, 16, 0, 0);
}

// all four weight tensors f32 -> bf16 in ONE launch.
// f32x4 segment sizes: conv 16384 | value 16384 | offset 7168 | out 16384
// total 56320 = 220 blocks * 256 threads exactly.
__global__ __launch_bounds__(256) void cast_all(
    const float* __restrict__ a0, u16* __restrict__ o0,
    const float* __restrict__ a1, u16* __restrict__ o1,
    const float* __restrict__ a2, u16* __restrict__ o2,
    const float* __restrict__ a3, u16* __restrict__ o3) {
  int i = blockIdx.x * 256 + threadIdx.x;
  const float* in; u16* out; int base;
  if (i < 16384)      { in = a0; out = o0; base = 0; }
  else if (i < 32768) { in = a1; out = o1; base = 16384; }
  else if (i < 39936) { in = a2; out = o2; base = 32768; }
  else                { in = a3; out = o3; base = 39936; }
  int j = i - base;
  f32x4 v = reinterpret_cast<const f32x4*>(in)[j];
  u32 lo = (u32)f2b(v[0]) | ((u32)f2b(v[1]) << 16);
  u32 hi = (u32)f2b(v[2]) | ((u32)f2b(v[3]) << 16);
  reinterpret_cast<u32*>(out)[2 * j]     = lo;
  reinterpret_cast<u32*>(out)[2 * j + 1] = hi;
}

// ---------------------------------------------------------------------------
// FUSED projection kernel v4 = r12 geometry (BM=128, best measured 66.4us)
// + stage-1 counted-vmcnt pipeline.
// r13 lesson: BM=64 regressed (MfmaUtil down, conflicts 2.3x) -> work-per-wave
// beats waves. Reverted to BM=128.
// Stage-1 pipeline: the 16 (ko,half) B-tiles stream through a ping-pong of
// {Bs, T+4096} (T is dead until the stage-1 epilogue -> free scratch); A
// ping-pongs {As, T} written one ko ahead. x-loads are issued BEFORE the
// B-issue so the compiler's wait-for-x (vmcnt<=2) drains the OLDER B(s) but
// leaves B(s+1) in flight; lgkmcnt(0) flushes A ds_writes pre-barrier;
// sched_barrier(0) brackets every raw s_barrier (rule #18). Per-accumulator
// MFMA order unchanged -> bit-identical output.
// Stage 2: counted-vmcnt ping-pong (r11-verified, bit-exact twice).
// LDS: T 64K + As 8K + Bs 8K = 80 KiB -> 2 blocks/CU; grid 512 = 2/CU.
// ---------------------------------------------------------------------------
__global__ __launch_bounds__(256, 2) void fused_proj(
    const float* __restrict__ X, const u16* __restrict__ Bc,
    const u16* __restrict__ Wcat,
    u16* __restrict__ Vv, float* __restrict__ Om,
    const float* __restrict__ vbias, const float* __restrict__ obias,
    const float* __restrict__ gamma, const float* __restrict__ beta,
    const float* __restrict__ mean, const float* __restrict__ var) {
  constexpr int BM = 128, BK = 32;
  __shared__ __align__(16) u16 T[BM * C_DIM];   // 64 KiB, swizzled
  __shared__ __align__(16) u16 As[BM * BK];     // 8 KiB
  __shared__ __align__(16) u16 Bs[BM * BK];     // 8 KiB
  const int tid  = threadIdx.x;
  const int lane = tid & 63;
  const int wave = tid >> 6;
  const int quad = lane >> 4;
  const int l16  = lane & 15;
  const int bm = blockIdx.x * BM;
  const int wm = (wave & 1) * 64;
  const int wn = (wave >> 1) * 64;
  const int img = bm >> 14;          // BM=128 divides HW
  const int hw0 = bm & (HW - 1);
  const int p2  = (tid & 63) * 2;    // pixel pair within tile
  const int hh  = tid >> 6;          // channel-slot 0..3 (8 ch each)
  const float* xb = X + (size_t)img * C_DIM * HW + hw0 + p2;

  // stage-1 scratch carved from T (dead until epilogue):
  u16* A1 = T;           // second A buffer (8 KiB)
  u16* B1 = T + 4096;    // second B buffer (8 KiB)

  auto issueB = [&](int s, u16* buf) {   // B-tile s: half (s&1), ko (s>>1)
    int h = s & 1, ko2 = s >> 1;
#pragma unroll
    for (int it = 0; it < 2; ++it) {
      int chunk = it * 256 + tid;
      int r  = chunk >> 2;
      int kk = (chunk & 3) << 3;
      async_cp16(Bc + (size_t)(h * 128 + r) * C_DIM + (ko2 * 32 + kk),
                 buf + (size_t)(it * 256 + wave * 64) * 8);
    }
  };
  auto writeA = [&](const f32x2 (&xv)[8], u16* dst) {
    u32x4 w0, w1;
#pragma unroll
    for (int j = 0; j < 4; ++j) {
      w0[j] = (u32)f2b(xv[2 * j].x) | ((u32)f2b(xv[2 * j + 1].x) << 16);
      w1[j] = (u32)f2b(xv[2 * j].y) | ((u32)f2b(xv[2 * j + 1].y) << 16);
    }
    u32x4* Ar = reinterpret_cast<u32x4*>(dst);
    int sw = hh ^ ((p2 >> 1) & 3);           // same for rows p2, p2+1
    Ar[p2 * 4 + sw]       = w0;
    Ar[(p2 + 1) * 4 + sw] = w1;
  };
  auto mfma_half = [&](const u16* Abuf, const u16* Bbuf, f32x4 (&acc)[4][4]) {
    const bf16x8* Apf = reinterpret_cast<const bf16x8*>(Abuf);
    const bf16x8* Bpf = reinterpret_cast<const bf16x8*>(Bbuf);
    bf16x8 af[4], bfr[4];
#pragma unroll
    for (int mi = 0; mi < 4; ++mi) {
      int r = wm + mi * 16 + l16;
      af[mi] = Apf[r * 4 + (quad ^ ((r >> 1) & 3))];
    }
#pragma unroll
    for (int ni = 0; ni < 4; ++ni)
      bfr[ni] = Bpf[(wn + ni * 16 + l16) * 4 + quad];
#pragma unroll
    for (int mi = 0; mi < 4; ++mi)
#pragma unroll
      for (int ni = 0; ni < 4; ++ni)
        acc[mi][ni] = __builtin_amdgcn_mfma_f32_16x16x32_bf16(
            af[mi], bfr[ni], acc[mi][ni], 0, 0, 0);
  };

  // ================= stage 1: T = silu(bn1(x @ wc^T)), pipelined
  f32x4 acc0[4][4] = {};
  f32x4 acc1[4][4] = {};
  {   // prologue: A(0) -> As, B(0) -> Bs, full drain
    f32x2 xv[8];
#pragma unroll
    for (int j = 0; j < 8; ++j)
      xv[j] = *reinterpret_cast<const f32x2*>(xb + (size_t)(hh * 8 + j) * HW);
    issueB(0, Bs);
    writeA(xv, As);
    __syncthreads();
  }
  for (int ko = 0; ko < 8; ++ko) {
    u16* Acur = (ko & 1) ? A1 : As;
    u16* Anxt = (ko & 1) ? As : A1;
    // ===== even stage s=2ko: consume Bs=B(2ko); issue B(2ko+1)->B1
    f32x2 xv[8];
    const bool haveA = (ko < 7);
    if (haveA) {
#pragma unroll
      for (int j = 0; j < 8; ++j)
        xv[j] = *reinterpret_cast<const f32x2*>(
            xb + (size_t)((ko + 1) * 32 + hh * 8 + j) * HW);
    }
    __builtin_amdgcn_sched_barrier(0);       // x-loads issued before B-issue
    issueB(2 * ko + 1, B1);
    if (haveA) writeA(xv, Anxt);             // waits x (vmcnt<=2), B(s+1) flies
    asm volatile("s_waitcnt vmcnt(2) lgkmcnt(0)" ::: "memory");
    __builtin_amdgcn_sched_barrier(0);
    __builtin_amdgcn_s_barrier();            // B(2ko) ready everywhere
    __builtin_amdgcn_sched_barrier(0);
    mfma_half(Acur, Bs, acc0);
    __builtin_amdgcn_sched_barrier(0);
    __builtin_amdgcn_s_barrier();            // all waves consumed Bs
    __builtin_amdgcn_sched_barrier(0);
    // ===== odd stage s=2ko+1: consume B1; issue B(2ko+2)->Bs
    if (ko < 7) {
      issueB(2 * ko + 2, Bs);
      asm volatile("s_waitcnt vmcnt(2)" ::: "memory");
    } else {
      asm volatile("s_waitcnt vmcnt(0)" ::: "memory");
    }
    __builtin_amdgcn_sched_barrier(0);
    __builtin_amdgcn_s_barrier();            // B(2ko+1) ready everywhere
    __builtin_amdgcn_sched_barrier(0);
    mfma_half(Acur, B1, acc1);
    __builtin_amdgcn_sched_barrier(0);
    __builtin_amdgcn_s_barrier();            // all waves consumed B1
    __builtin_amdgcn_sched_barrier(0);
  }
  // ---- epilogue: bn1 + silu -> T (LDS, swizzled), both halves
  auto epi1 = [&](f32x4 (&acc)[4][4], int bn) {
#pragma unroll
    for (int ni = 0; ni < 4; ++ni) {
      int n = bn + wn + ni * 16 + l16;
      float sc = gamma[n] * rsqrtf(var[n] + EPSV);
      float sh = beta[n] - mean[n] * sc;
#pragma unroll
      for (int mi = 0; mi < 4; ++mi) {
        int row = wm + mi * 16 + quad * 4;
#pragma unroll
        for (int i = 0; i < 4; ++i) {
          float y = acc[mi][ni][i] * sc + sh;
          y = y / (1.f + __expf(-y));   // silu
          int rr = row + i;
          T[rr * C_DIM + (((n >> 3) ^ (rr & 15)) << 3) + (n & 7)] = f2b(y);
        }
      }
    }
  };
  epi1(acc0, 0);
  epi1(acc1, 128);
  __syncthreads();   // T complete; As/Bs free for stage 2

  // ================= stage 2: [vv|om] = T @ wcat^T, counted-vmcnt dbuf
  auto stage2 = [&](u16* buf, int n0, int ko) {
#pragma unroll
    for (int it = 0; it < 2; ++it) {
      int chunk = it * 256 + tid;
      int r  = chunk >> 2;
      int kk = (chunk & 3) << 3;
      int br = n0 + r; if (br >= NCAT) br = NCAT - 1;   // clamp pad rows
      async_cp16(Wcat + (size_t)br * C_DIM + (ko + kk),
                 buf + (size_t)(it * 256 + wave * 64) * 8);
    }
  };
  for (int nc = 0; nc < 3; ++nc) {
    const int n0 = nc * 128;
    f32x4 acc[4][4] = {};
    stage2(As, n0, 0);                       // prologue -> buf0
    for (int koi = 0; koi < 8; ++koi) {
      const u16* cur = (koi & 1) ? Bs : As;
      u16*       nxt = (koi & 1) ? As : Bs;
      if (koi < 7) {
        stage2(nxt, n0, (koi + 1) * BK);     // keep 2 loads in flight
        asm volatile("s_waitcnt vmcnt(2)" ::: "memory");   // cur buf landed
      } else {
        asm volatile("s_waitcnt vmcnt(0)" ::: "memory");
      }
      __builtin_amdgcn_sched_barrier(0);
      __builtin_amdgcn_s_barrier();          // all waves: cur ready
      __builtin_amdgcn_sched_barrier(0);
      const bf16x8* Bpf = reinterpret_cast<const bf16x8*>(cur);
      bf16x8 af[4], bfr[4];
#pragma unroll
      for (int mi = 0; mi < 4; ++mi) {
        int row = wm + mi * 16 + l16;
        int ch  = koi * 4 + quad;            // wanted 8-elem chunk
        af[mi] = *reinterpret_cast<const bf16x8*>(
            &T[row * C_DIM + ((ch ^ (row & 15)) << 3)]);
      }
#pragma unroll
      for (int ni = 0; ni < 4; ++ni)
        bfr[ni] = Bpf[(wn + ni * 16 + l16) * 4 + quad];
#pragma unroll
      for (int mi = 0; mi < 4; ++mi)
#pragma unroll
        for (int ni = 0; ni < 4; ++ni)
          acc[mi][ni] = __builtin_amdgcn_mfma_f32_16x16x32_bf16(
              af[mi], bfr[ni], acc[mi][ni], 0, 0, 0);
      __builtin_amdgcn_sched_barrier(0);
      __builtin_amdgcn_s_barrier();          // all waves consumed cur
    }
    // ---- epilogue: value -> bf16 NHWC, offset -> f32 (M,112)
#pragma unroll
    for (int ni = 0; ni < 4; ++ni) {
      int n = n0 + wn + ni * 16 + l16;
      if (n < C_DIM) {
        float sh = vbias[n];
#pragma unroll
        for (int mi = 0; mi < 4; ++mi) {
          int mrow = bm + wm + mi * 16 + quad * 4;
#pragma unroll
          for (int i = 0; i < 4; ++i)
            Vv[(size_t)(mrow + i) * C_DIM + n] = f2b(acc[mi][ni][i] + sh);
        }
      } else {
        int col = n - C_DIM;
        bool ok = col < PADOFF;
        float sh = ok ? obias[col] : 0.f;
#pragma unroll
        for (int mi = 0; mi < 4; ++mi) {
          int mrow = bm + wm + mi * 16 + quad * 4;
#pragma unroll
          for (int i = 0; i < 4; ++i)
            if (ok) Om[(size_t)(mrow + i) * PADOFF + col] = acc[mi][ni][i] + sh;
        }
      }
    }
  }
}

// ---------------------------------------------------------------------------
// Output GEMM v2 (r12, proven -8.8us): counted-vmcnt double-buffer, BK=32
// ping-pong, LDS 32 KiB. Mid-loop s_waitcnt vmcnt(4); raw s_barrier +
// sched_barrier(0) fences. Bit-identical accumulation.
// Epilogue: bias+bn2+silu -> f32 NCHW DIRECT.
// ---------------------------------------------------------------------------
__global__ __launch_bounds__(256) void gemm_out(
    const u16* __restrict__ A, const u16* __restrict__ B,
    float* __restrict__ Cf,
    const float* __restrict__ bias,
    const float* __restrict__ gamma, const float* __restrict__ beta,
    const float* __restrict__ mean, const float* __restrict__ var) {
  constexpr int BM = 128, BK = 32;
  __shared__ __align__(16) u16 As[2][BM * BK];   // 2 x 8 KiB
  __shared__ __align__(16) u16 Bs[2][BM * BK];   // 2 x 8 KiB
  const int tid  = threadIdx.x;
  const int lane = tid & 63;
  const int wave = tid >> 6;
  const int quad = lane >> 4;
  const int l16  = lane & 15;
  const int bm = blockIdx.x * BM;
  const int bn = blockIdx.y * BM;
  const int wm = (wave & 1) * 64;
  const int wn = (wave >> 1) * 64;

  auto stage = [&](int buf, int ko) {
#pragma unroll
    for (int it = 0; it < 2; ++it) {
      int chunk = it * 256 + tid;          // 16B chunk id, 512 per tile
      int r  = chunk >> 2;                 // tile row 0..127
      int kk = (chunk & 3) << 3;           // k offset 0,8,16,24
      async_cp16(A + (size_t)(bm + r) * C_DIM + (ko + kk),
                 &As[buf][(it * 256 + wave * 64) * 8]);
      async_cp16(B + (size_t)(bn + r) * C_DIM + (ko + kk),
                 &Bs[buf][(it * 256 + wave * 64) * 8]);
    }
  };

  f32x4 acc[4][4] = {};

  stage(0, 0);                             // prologue -> buf0
  for (int t = 0; t < 8; ++t) {
    const int cur = t & 1;
    if (t < 7) {
      stage(cur ^ 1, (t + 1) * BK);        // keep 4 loads in flight
      asm volatile("s_waitcnt vmcnt(4)" ::: "memory");   // tile-t loads landed
    } else {
      asm volatile("s_waitcnt vmcnt(0)" ::: "memory");
    }
    __builtin_amdgcn_sched_barrier(0);
    __builtin_amdgcn_s_barrier();          // all waves: cur ready
    __builtin_amdgcn_sched_barrier(0);
    const bf16x8* Ap = reinterpret_cast<const bf16x8*>(As[cur]);
    const bf16x8* Bp = reinterpret_cast<const bf16x8*>(Bs[cur]);
    bf16x8 af[4], bfr[4];
#pragma unroll
    for (int mi = 0; mi < 4; ++mi) af[mi] = Ap[(wm + mi * 16 + l16) * 4 + quad];
#pragma unroll
    for (int ni = 0; ni < 4; ++ni) bfr[ni] = Bp[(wn + ni * 16 + l16) * 4 + quad];
#pragma unroll
    for (int mi = 0; mi < 4; ++mi)
#pragma unroll
      for (int ni = 0; ni < 4; ++ni)
        acc[mi][ni] = __builtin_amdgcn_mfma_f32_16x16x32_bf16(
            af[mi], bfr[ni], acc[mi][ni], 0, 0, 0);
    __builtin_amdgcn_sched_barrier(0);
    __builtin_amdgcn_s_barrier();          // all waves consumed cur
  }

#pragma unroll
  for (int ni = 0; ni < 4; ++ni) {
    int n = bn + wn + ni * 16 + l16;
    float sc = gamma[n] * rsqrtf(var[n] + EPSV);
    float sh = beta[n] - mean[n] * sc + bias[n] * sc;
#pragma unroll
    for (int mi = 0; mi < 4; ++mi) {
      int mrow = bm + wm + mi * 16 + quad * 4;
      int img = mrow >> 14;            // BM=128 divides HW -> uniform img
      int hw  = mrow & (HW - 1);
      f32x4 y;
#pragma unroll
      for (int i = 0; i < 4; ++i) {
        float z = acc[mi][ni][i] * sc + sh;
        y[i] = z / (1.f + __expf(-z));   // silu
      }
      *reinterpret_cast<f32x4*>(
          Cf + (size_t)img * C_DIM * HW + (size_t)n * HW + hw) = y;
    }
  }
}

// ---------------------------------------------------------------------------
// Deformable sampling, v6 (proven r4: 40 VGPR, occ 50%, ~51us):
// dot2-packed inner loop — v_perm pairs horizontal corners' bf16 channels,
// v_dot2_f32_bf16 applies both corner weights in one instr; weights packed
// via v_cvt_pk_bf16_f32; output packed via cvt_pk. XCD swizzle for L2.
// v: (M, C) NHWC bf16 ; om: (M, 112) f32 [per g: 18 offsets(x,y), 9 masks]
// ---------------------------------------------------------------------------
__global__ __launch_bounds__(256) void dcn_sample(
    const u16* __restrict__ v, const float* __restrict__ om,
    u16* __restrict__ outp) {
  __shared__ float sm[16 * PADOFF];   // 1792 f32 = 7 KiB
  const int tid = threadIdx.x;
  // XCD swizzle (gridDim.x = 4096, divisible by 8 -> bijective)
  const int bid = blockIdx.x;
  const int cpx = gridDim.x >> 3;               // blocks per XCD chunk
  const int wg  = (bid & 7) * cpx + (bid >> 3);
  const int m0  = wg * 16;
  {
    const float* src = om + (size_t)m0 * PADOFF;
#pragma unroll
    for (int i = 0; i < 7; ++i) sm[tid + i * 256] = src[tid + i * 256];
  }
  __syncthreads();
  const int c4 = tid & 3;            // 16-channel slice within group
  const int g  = (tid >> 2) & 3;
  const int pl = tid >> 4;           // pixel within block
  const int m  = m0 + pl;
  const int n  = m >> 14;            // HW = 2^14
  const int hw = m & (HW - 1);
  const int h = hw >> 7, w = hw & 127;
  const float* p = sm + pl * PADOFF + g * 27;
  const u16* vb = v + (size_t)n * HW * C_DIM + g * CG + c4 * 16;
  float acc[16] = {};
#pragma unroll
  for (int k = 0; k < 9; ++k) {
    const int di = k / 3 - 1, dj = k % 3 - 1;
    float ox = p[2 * k], oy = p[2 * k + 1], mk = p[18 + k];
    float lh = (float)(h + di) + oy;
    float lw = (float)(w + dj) + ox;
    float fh = floorf(lh), fw = floorf(lw);
    float dh = lh - fh, dw = lw - fw;
    int h0 = (int)fh, w0 = (int)fw;
    float wy0 = (1.f - dh) * mk, wy1 = dh * mk;
    float wx0 = 1.f - dw, wx1 = dw;
    bool okw0 = (u32)w0 < (u32)W_DIM;
    bool okw1 = (u32)(w0 + 1) < (u32)W_DIM;
    int w0c = min(max(w0, 0), W_DIM - 1);
    int w1c = min(max(w0 + 1, 0), W_DIM - 1);
#pragma unroll
    for (int cy = 0; cy < 2; ++cy) {
      int hh = h0 + cy;
      bool okh = (u32)hh < (u32)H_DIM;
      int hc = min(max(hh, 0), H_DIM - 1);
      const u16* rowp = vb + (size_t)(hc << 7) * C_DIM;
      const u16* qA = rowp + (size_t)w0c * C_DIM;
      const u16* qB = rowp + (size_t)w1c * C_DIM;
      u32x4 a0 = *reinterpret_cast<const u32x4*>(qA);
      u32x4 a1 = *reinterpret_cast<const u32x4*>(qA + 8);
      u32x4 b0 = *reinterpret_cast<const u32x4*>(qB);
      u32x4 b1 = *reinterpret_cast<const u32x4*>(qB + 8);
      float wyc = (cy == 0) ? wy0 : wy1;
      float wtA = (okh && okw0) ? wyc * wx0 : 0.f;
      float wtB = (okh && okw1) ? wyc * wx1 : 0.f;
      u32 wp;
      asm("v_cvt_pk_bf16_f32 %0, %1, %2" : "=v"(wp) : "v"(wtA), "v"(wtB));
#pragma unroll
      for (int j = 0; j < 4; ++j) {
        u32 lo0 = __builtin_amdgcn_perm(a0[j], b0[j], 0x01000504u);
        u32 hi0 = __builtin_amdgcn_perm(a0[j], b0[j], 0x03020706u);
        u32 lo1 = __builtin_amdgcn_perm(a1[j], b1[j], 0x01000504u);
        u32 hi1 = __builtin_amdgcn_perm(a1[j], b1[j], 0x03020706u);
        asm("v_dot2_f32_bf16 %0, %1, %2, %3"
            : "=v"(acc[2 * j]) : "v"(lo0), "v"(wp), "v"(acc[2 * j]));
        asm("v_dot2_f32_bf16 %0, %1, %2, %3"
            : "=v"(acc[2 * j + 1]) : "v"(hi0), "v"(wp), "v"(acc[2 * j + 1]));
        asm("v_dot2_f32_bf16 %0, %1, %2, %3"
            : "=v"(acc[8 + 2 * j]) : "v"(lo1), "v"(wp), "v"(acc[8 + 2 * j]));
        asm("v_dot2_f32_bf16 %0, %1, %2, %3"
            : "=v"(acc[8 + 2 * j + 1]) : "v"(hi1), "v"(wp), "v"(acc[8 + 2 * j + 1]));
      }
    }
  }
  u32x4 r0, r1;
#pragma unroll
  for (int j = 0; j < 4; ++j) {
    u32 pa, pb;
    asm("v_cvt_pk_bf16_f32 %0, %1, %2"
        : "=v"(pa) : "v"(acc[2 * j]), "v"(acc[2 * j + 1]));
    asm("v_cvt_pk_bf16_f32 %0, %1, %2"
        : "=v"(pb) : "v"(acc[8 + 2 * j]), "v"(acc[8 + 2 * j + 1]));
    r0[j] = pa; r1[j] = pb;
  }
  u16* o = outp + (size_t)m * C_DIM + g * CG + c4 * 16;
  *reinterpret_cast<u32x4*>(o)     = r0;
  *reinterpret_cast<u32x4*>(o + 8) = r1;
}

// ---------------------------------------------------------------------------
extern "C" void kernel_launch(void* const* d_in, const int* in_sizes, int n_in,
                              void* d_out, int out_size, void* d_ws, size_t ws_size,
                              hipStream_t stream) {
  const float* x        = (const float*)d_in[0];
  const float* conv_w   = (const float*)d_in[1];
  const float* bn1_g    = (const float*)d_in[2];
  const float* bn1_b    = (const float*)d_in[3];
  const float* bn1_m    = (const float*)d_in[4];
  const float* bn1_v    = (const float*)d_in[5];
  const float* value_w  = (const float*)d_in[6];
  const float* value_b  = (const float*)d_in[7];
  const float* offset_w = (const float*)d_in[8];
  const float* offset_b = (const float*)d_in[9];
  const float* out_w    = (const float*)d_in[10];
  const float* out_b    = (const float*)d_in[11];
  const float* bn2_g    = (const float*)d_in[12];
  const float* bn2_b    = (const float*)d_in[13];
  const float* bn2_m    = (const float*)d_in[14];
  const float* bn2_v    = (const float*)d_in[15];

  char* ws = (char*)d_ws;
  u16*   vv   = (u16*)(ws);                    // 32 MiB  (value proj)
  float* om   = (float*)(ws + 33554432);       // 28 MiB  (offset+mask f32)
  u16*   dcn  = (u16*)(ws + 67108864);         // 32 MiB  (dcn output)
  u16*   wc   = (u16*)(ws + 100663296);        // conv_w bf16 (128 KiB)
  u16*   wcat = (u16*)(ws + 100794368);        // [value_w; offset_w] bf16
  u16*   wout = (u16*)(ws + 100982784);        // out_w bf16 (128 KiB)
  float* outp = (float*)d_out;                 // final output is f32

  // W: all weights f32 -> bf16 in one launch (value+offset concatenated)
  cast_all<<<220, 256, 0, stream>>>(conv_w, wc, value_w, wcat,
                                    offset_w, wcat + 65536, out_w, wout);

  // K1+K2 fused: x -> (conv+bn1+silu in LDS) -> [vv | om]   (BM=128, 2/CU)
  fused_proj<<<dim3(M_TOT / 128), 256, 0, stream>>>(
      x, wc, wcat, vv, om, value_b, offset_b,
      bn1_g, bn1_b, bn1_m, bn1_v);
  // K4: deformable bilinear sampling (16 px / block)
  dcn_sample<<<dim3(M_TOT / 16), 256, 0, stream>>>(vv, om, dcn);
  // K5: d_out = silu(bn2(dcn @ out_w^T + out_b))  f32 NCHW DIRECT
  gemm_out<<<dim3(M_TOT / 128, 2), 256, 0, stream>>>(
      dcn, wout, outp, out_b, bn2_g, bn2_b, bn2_m, bn2_v);
}